// Round 1
// baseline (50017.386 us; speedup 1.0000x reference)
//
#include <hip/hip_runtime.h>
#include <hip/hip_bf16.h>
#include <cstddef>

// Problem constants
constexpr int B_ = 4, T_ = 1024, D_ = 768, H_ = 12, L_ = 12, V_ = 50257;
constexpr int HD_ = D_ / H_;      // 64
constexpr int FF_ = 4 * D_;       // 3072
constexpr int BT_ = B_ * T_;      // 4096
constexpr float EPS_ = 1e-5f;

// ---------------- block reduction helpers (256 threads = 4 waves) ----------
__device__ __forceinline__ float block_reduce_sum(float val, float* sdata) {
    #pragma unroll
    for (int off = 32; off > 0; off >>= 1) val += __shfl_down(val, off, 64);
    int lane = threadIdx.x & 63, wid = threadIdx.x >> 6;
    if (lane == 0) sdata[wid] = val;
    __syncthreads();
    if (threadIdx.x == 0) sdata[0] = sdata[0] + sdata[1] + sdata[2] + sdata[3];
    __syncthreads();
    float r = sdata[0];
    __syncthreads();
    return r;
}

__device__ __forceinline__ float block_reduce_max(float val, float* sdata) {
    #pragma unroll
    for (int off = 32; off > 0; off >>= 1) val = fmaxf(val, __shfl_down(val, off, 64));
    int lane = threadIdx.x & 63, wid = threadIdx.x >> 6;
    if (lane == 0) sdata[wid] = val;
    __syncthreads();
    if (threadIdx.x == 0) sdata[0] = fmaxf(fmaxf(sdata[0], sdata[1]), fmaxf(sdata[2], sdata[3]));
    __syncthreads();
    float r = sdata[0];
    __syncthreads();
    return r;
}

// ---------------- embedding: x = tok_emb[idx] + pos_emb ---------------------
__global__ __launch_bounds__(256) void embed_kernel(
    const int* __restrict__ idx, const float* __restrict__ tok,
    const float* __restrict__ pos, float* __restrict__ x) {
    int i = blockIdx.x * 256 + threadIdx.x;       // float4 index, total BT*D/4
    int elem = i * 4;
    int row = elem / D_;
    int d = elem % D_;
    int tokid = idx[row];
    float4 a = *(const float4*)(tok + (size_t)tokid * D_ + d);
    float4 p = *(const float4*)(pos + (size_t)(row % T_) * D_ + d);
    a.x += p.x; a.y += p.y; a.z += p.z; a.w += p.w;
    *(float4*)(x + (size_t)row * D_ + d) = a;
}

// ---------------- layernorm: one block (256 thr) per row --------------------
__global__ __launch_bounds__(256) void ln_kernel(
    const float* __restrict__ in, float* __restrict__ out,
    const float* __restrict__ g, const float* __restrict__ b) {
    int row = blockIdx.x;
    const float* xr = in + (size_t)row * D_;
    __shared__ float sdata[8];
    float s = 0.f;
    for (int d = threadIdx.x; d < D_; d += 256) s += xr[d];
    float mean = block_reduce_sum(s, sdata) * (1.0f / D_);
    float vs = 0.f;
    for (int d = threadIdx.x; d < D_; d += 256) { float t = xr[d] - mean; vs += t * t; }
    float var = block_reduce_sum(vs, sdata) * (1.0f / D_);
    float rs = 1.0f / sqrtf(var + EPS_);
    for (int d = threadIdx.x; d < D_; d += 256)
        out[(size_t)row * D_ + d] = (xr[d] - mean) * rs * g[d] + b[d];
}

// ---------------- fp32 SGEMM: C[M,N] = A[M,K] @ W[K,N] (+bias)(gelu)(+res) --
// 128x128 tile, BK=8, 256 threads, 8x8 per thread.
// M must be a multiple of 128 and K a multiple of 8 (true for all calls).
__device__ __forceinline__ float gelu_exact(float x) {
    return 0.5f * x * (1.0f + erff(x * 0.70710678118654752f));
}

template<bool BIAS, bool GELU, bool RES>
__global__ __launch_bounds__(256) void sgemm_kernel(
    const float* __restrict__ A, const float* __restrict__ W,
    const float* __restrict__ bias, const float* res,
    float* C, int M, int N, int K) {
    constexpr int BM = 128, BN = 128, BK = 8, TM = 8, TN = 8;
    __shared__ float As[BK][BM];
    __shared__ float Bs[BK][BN];
    int tid = threadIdx.x;
    int tx = tid % 16, ty = tid / 16;
    int row0 = blockIdx.y * BM, col0 = blockIdx.x * BN;

    float acc[TM][TN];
    #pragma unroll
    for (int i = 0; i < TM; ++i)
        #pragma unroll
        for (int j = 0; j < TN; ++j) acc[i][j] = 0.f;

    // load mapping
    int a_row = tid >> 1;            // 0..127
    int a_col4 = (tid & 1) * 4;      // 0 or 4
    int b_row = tid >> 5;            // 0..7
    int b_col4 = (tid & 31) * 4;     // 0..124

    for (int k0 = 0; k0 < K; k0 += BK) {
        // A tile (no M/K guards needed)
        float4 av = *(const float4*)(A + (size_t)(row0 + a_row) * K + k0 + a_col4);
        As[a_col4 + 0][a_row] = av.x;
        As[a_col4 + 1][a_row] = av.y;
        As[a_col4 + 2][a_row] = av.z;
        As[a_col4 + 3][a_row] = av.w;
        // W tile with N guard
        int gn = col0 + b_col4;
        float4 bv;
        const float* wrow = W + (size_t)(k0 + b_row) * N;
        if (gn + 3 < N) {
            bv = *(const float4*)(wrow + gn);
        } else {
            bv.x = (gn + 0 < N) ? wrow[gn + 0] : 0.f;
            bv.y = (gn + 1 < N) ? wrow[gn + 1] : 0.f;
            bv.z = (gn + 2 < N) ? wrow[gn + 2] : 0.f;
            bv.w = (gn + 3 < N) ? wrow[gn + 3] : 0.f;
        }
        *(float4*)&Bs[b_row][b_col4] = bv;
        __syncthreads();

        #pragma unroll
        for (int kk = 0; kk < BK; ++kk) {
            float a[TM], b[TN];
            #pragma unroll
            for (int i = 0; i < TM; ++i) a[i] = As[kk][ty * TM + i];
            #pragma unroll
            for (int j = 0; j < TN; ++j) b[j] = Bs[kk][tx * TN + j];
            #pragma unroll
            for (int i = 0; i < TM; ++i)
                #pragma unroll
                for (int j = 0; j < TN; ++j) acc[i][j] += a[i] * b[j];
        }
        __syncthreads();
    }

    #pragma unroll
    for (int i = 0; i < TM; ++i) {
        int gr = row0 + ty * TM + i;
        #pragma unroll
        for (int j = 0; j < TN; ++j) {
            int gc = col0 + tx * TN + j;
            if (gc < N) {
                float cv = acc[i][j];
                if (BIAS) cv += bias[gc];
                if (GELU) cv = gelu_exact(cv);
                if (RES)  cv += res[(size_t)gr * N + gc];
                C[(size_t)gr * N + gc] = cv;
            }
        }
    }
}

// ---------------- fused causal attention: one block per (b,h,t) -------------
__global__ __launch_bounds__(256) void attn_kernel(
    const float* __restrict__ q, const float* __restrict__ k,
    const float* __restrict__ v, float* __restrict__ out) {
    int t = blockIdx.x, h = blockIdx.y, b = blockIdx.z;
    __shared__ float qs[HD_];
    __shared__ float scr[T_];
    __shared__ float red[8];
    __shared__ float part[4][HD_];

    size_t base = (size_t)b * T_ * D_ + (size_t)h * HD_;
    if (threadIdx.x < HD_) qs[threadIdx.x] = q[base + (size_t)t * D_ + threadIdx.x];
    __syncthreads();

    int nS = t + 1;
    const float scale = 0.125f;  // 1/sqrt(64)
    for (int s = threadIdx.x; s < nS; s += 256) {
        const float* kr = k + base + (size_t)s * D_;
        float dot = 0.f;
        #pragma unroll
        for (int d = 0; d < HD_; d += 4) {
            float4 kv = *(const float4*)(kr + d);
            float4 qv = *(const float4*)(qs + d);
            dot += kv.x * qv.x + kv.y * qv.y + kv.z * qv.z + kv.w * qv.w;
        }
        scr[s] = dot * scale;
    }
    __syncthreads();

    float m = -INFINITY;
    for (int s = threadIdx.x; s < nS; s += 256) m = fmaxf(m, scr[s]);
    m = block_reduce_max(m, red);

    float sum = 0.f;
    for (int s = threadIdx.x; s < nS; s += 256) {
        float e = expf(scr[s] - m);
        scr[s] = e;
        sum += e;
    }
    sum = block_reduce_sum(sum, red);   // includes barrier: scr[] updates visible
    float inv = 1.0f / sum;

    int d = threadIdx.x & 63;
    int grp = threadIdx.x >> 6;
    float accv = 0.f;
    for (int s = grp; s < nS; s += 4)
        accv += scr[s] * v[base + (size_t)s * D_ + d];
    part[grp][d] = accv;
    __syncthreads();
    if (threadIdx.x < HD_) {
        float o = (part[0][d] + part[1][d] + part[2][d] + part[3][d]) * inv;
        out[base + (size_t)t * D_ + d] = o;
    }
}

// ---------------- loss -------------------------------------------------------
__global__ void zero_kernel(float* p) { if (threadIdx.x == 0) *p = 0.f; }

__global__ __launch_bounds__(256) void loss_kernel(
    const float* __restrict__ logits, const int* __restrict__ targets,
    float* loss_out) {
    int row = blockIdx.x;
    const float* lr = logits + (size_t)row * V_;
    __shared__ float red[8];
    float m = -INFINITY;
    for (int j = threadIdx.x; j < V_; j += 256) m = fmaxf(m, lr[j]);
    m = block_reduce_max(m, red);
    float s = 0.f;
    for (int j = threadIdx.x; j < V_; j += 256) s += expf(lr[j] - m);
    s = block_reduce_sum(s, red);
    if (threadIdx.x == 0) {
        int tgt = targets[row];
        float lp = lr[tgt] - m - logf(s);
        atomicAdd(loss_out, -lp * (1.0f / (float)BT_));
    }
}

// ---------------- launch -----------------------------------------------------
extern "C" void kernel_launch(void* const* d_in, const int* in_sizes, int n_in,
                              void* d_out, int out_size, void* d_ws, size_t ws_size,
                              hipStream_t stream) {
    const int*   idx     = (const int*)d_in[0];
    const int*   targets = (const int*)d_in[1];
    const float* tok_emb = (const float*)d_in[2];
    const float* pos_emb = (const float*)d_in[3];
    const float* Wq      = (const float*)d_in[4];
    const float* Wk      = (const float*)d_in[5];
    const float* Wv      = (const float*)d_in[6];
    const float* Wo      = (const float*)d_in[7];
    const float* bo      = (const float*)d_in[8];
    const float* ln1_g   = (const float*)d_in[9];
    const float* ln1_b   = (const float*)d_in[10];
    const float* ln2_g   = (const float*)d_in[11];
    const float* ln2_b   = (const float*)d_in[12];
    const float* W1      = (const float*)d_in[13];
    const float* b1      = (const float*)d_in[14];
    const float* W2      = (const float*)d_in[15];
    const float* b2      = (const float*)d_in[16];
    const float* lnf_g   = (const float*)d_in[17];
    const float* lnf_b   = (const float*)d_in[18];
    const float* Wh      = (const float*)d_in[19];
    const float* bh      = (const float*)d_in[20];

    float* out = (float*)d_out;               // logits [BT,V] then loss [1]
    float* loss_ptr = out + (size_t)BT_ * V_;

    // workspace layout (floats): x, h, q, k, v, attn  (ff aliases q..attn)
    float* ws    = (float*)d_ws;
    float* x     = ws;
    float* h     = x  + (size_t)BT_ * D_;
    float* qb    = h  + (size_t)BT_ * D_;
    float* kb    = qb + (size_t)BT_ * D_;
    float* vb    = kb + (size_t)BT_ * D_;
    float* attnb = vb + (size_t)BT_ * D_;
    float* ff    = qb;  // BT*FF floats == exactly the q..attn region (4*BT*D)

    dim3 blk(256);
    dim3 gD(D_ / 128, BT_ / 128);       // (6, 32)
    dim3 gFF(FF_ / 128, BT_ / 128);     // (24, 32)
    dim3 gV((V_ + 127) / 128, BT_ / 128); // (393, 32)
    dim3 gAttn(T_, H_, B_);

    embed_kernel<<<(BT_ * D_ / 4) / 256, blk, 0, stream>>>(idx, tok_emb, pos_emb, x);

    for (int l = 0; l < L_; ++l) {
        const float* wq = Wq + (size_t)l * D_ * D_;
        const float* wk = Wk + (size_t)l * D_ * D_;
        const float* wv = Wv + (size_t)l * D_ * D_;
        const float* wo = Wo + (size_t)l * D_ * D_;
        const float* w1 = W1 + (size_t)l * D_ * FF_;
        const float* w2 = W2 + (size_t)l * FF_ * D_;

        ln_kernel<<<BT_, blk, 0, stream>>>(x, h, ln1_g + l * D_, ln1_b + l * D_);
        sgemm_kernel<false, false, false><<<gD, blk, 0, stream>>>(h, wq, nullptr, nullptr, qb, BT_, D_, D_);
        sgemm_kernel<false, false, false><<<gD, blk, 0, stream>>>(h, wk, nullptr, nullptr, kb, BT_, D_, D_);
        sgemm_kernel<false, false, false><<<gD, blk, 0, stream>>>(h, wv, nullptr, nullptr, vb, BT_, D_, D_);
        attn_kernel<<<gAttn, blk, 0, stream>>>(qb, kb, vb, attnb);
        // x = x + attn @ Wo + bo
        sgemm_kernel<true, false, true><<<gD, blk, 0, stream>>>(attnb, wo, bo + l * D_, x, x, BT_, D_, D_);
        ln_kernel<<<BT_, blk, 0, stream>>>(x, h, ln2_g + l * D_, ln2_b + l * D_);
        // ff = gelu(h @ W1 + b1)
        sgemm_kernel<true, true, false><<<gFF, blk, 0, stream>>>(h, w1, b1 + l * FF_, nullptr, ff, BT_, FF_, D_);
        // x = x + ff @ W2 + b2
        sgemm_kernel<true, false, true><<<gD, blk, 0, stream>>>(ff, w2, b2 + l * D_, x, x, BT_, D_, FF_);
    }

    ln_kernel<<<BT_, blk, 0, stream>>>(x, h, lnf_g, lnf_b);
    // logits = h @ Wh + bh  -> d_out
    sgemm_kernel<true, false, false><<<gV, blk, 0, stream>>>(h, Wh, bh, nullptr, out, BT_, V_, D_);

    zero_kernel<<<1, 64, 0, stream>>>(loss_ptr);
    loss_kernel<<<BT_, blk, 0, stream>>>(out, targets, loss_ptr);
}